// Round 1
// baseline (30042.688 us; speedup 1.0000x reference)
//
#include <hip/hip_runtime.h>
#include <math.h>

#pragma clang fp contract(off)

#define NS 1024
#define NU 8192
#define FINF __builtin_huge_valf()

// ---------------------------------------------------------------------------
// Kernel 0: detect mask encoding. Words all in {0,1,0x3F800000} => 4-byte
// elements (int32 or float32; nonzero-check is identical). Anything else =>
// 1-byte elements.
// ---------------------------------------------------------------------------
__global__ void detect_kernel(const unsigned* __restrict__ m, int* __restrict__ flag) {
    __shared__ int s_any;
    if (threadIdx.x == 0) s_any = 0;
    __syncthreads();
    int bad = 0;
    for (int i = threadIdx.x; i < 65536; i += 256) {
        unsigned v = m[i];
        bad |= !(v == 0u || v == 1u || v == 0x3F800000u);
    }
    if (bad) s_any = 1;   // benign same-value race
    __syncthreads();
    if (threadIdx.x == 0) flag[0] = s_any;
}

// ---------------------------------------------------------------------------
// Kernel 1: stable rank sort of users[:,2]  ->  order[rank] = i
// Matches jnp.argsort (stable ascending) via (key, index) lexicographic rank.
// ---------------------------------------------------------------------------
__global__ void rank_kernel(const float* __restrict__ users, int* __restrict__ order) {
    __shared__ float keys[2048];
    const int i = blockIdx.x * 256 + threadIdx.x;
    const float key = users[i * 6 + 2];
    int rank = 0;
    for (int base = 0; base < NU; base += 2048) {
        __syncthreads();
        for (int k = threadIdx.x; k < 2048; k += 256)
            keys[k] = users[(base + k) * 6 + 2];
        __syncthreads();
        for (int k = 0; k < 2048; ++k) {
            float kj = keys[k];
            int j = base + k;
            rank += (kj < key) || ((kj == key) && (j < i));
        }
    }
    order[rank] = i;
}

// ---------------------------------------------------------------------------
// Kernel 2: the sequential allocator. 1 block x 256 threads, 4 servers/thread.
// All per-server state lives in registers; fuzzy/B are recomputed only for
// the chosen server (state changes one server per step).
// ---------------------------------------------------------------------------
__global__ __launch_bounds__(256, 1)
void alloc_kernel(const float* __restrict__ servers,
                  const float* __restrict__ users,
                  const void*  __restrict__ masksv,
                  const int*   __restrict__ wsi,
                  float* __restrict__ out) {
    const int tid  = threadIdx.x;
    const int lane = tid & 63;
    const int wid  = tid >> 6;
    const int byteMode = wsi[0];
    const int* __restrict__ order_g = wsi + 64;
    const unsigned char* __restrict__ mbytes = (const unsigned char*)masksv;
    const int*           __restrict__ mwords = (const int*)masksv;

    __shared__ int   s_order[NU];
    __shared__ float rA[4][6];
    __shared__ float rB[4];
    __shared__ float rCv[4];
    __shared__ int   rCi[4];

    for (int i = tid; i < NU; i += 256) s_order[i] = order_g[i];

    // per-thread state: servers sbase..sbase+3
    float c[4][4], t[4][4], f[4][4], B[4], us[4];
    const int sbase = tid * 4;
    #pragma unroll
    for (int j = 0; j < 4; ++j) {
        #pragma unroll
        for (int k = 0; k < 4; ++k) {
            float cv = servers[(sbase + j) * 7 + 3 + k];
            c[j][k] = cv;
            t[j][k] = cv;
            f[j][k] = 0.0f;      // rem=0 -> x=0 -> fuzzy=0
        }
        us[j] = 0.0f;
        B[j]  = 0.0f;            // 1 - mean(c/c) = 0 exactly
    }
    __syncthreads();             // s_order ready

    float allocCnt = 0.0f;       // tracked by tid 0 (uniform values)

    // current-step user data (software prefetch, one step ahead)
    int   mcur;
    float w0, w1, w2, w3;
    {
        int u0 = s_order[0];
        if (byteMode) {
            uchar4 mv = *(const uchar4*)(mbytes + (size_t)u0 * NS + sbase);
            mcur = (mv.x ? 1 : 0) | (mv.y ? 2 : 0) | (mv.z ? 4 : 0) | (mv.w ? 8 : 0);
        } else {
            int4 mv = *(const int4*)(mwords + (size_t)u0 * NS + sbase);
            mcur = (mv.x ? 1 : 0) | (mv.y ? 2 : 0) | (mv.z ? 4 : 0) | (mv.w ? 8 : 0);
        }
        float2 a  = *(const float2*)(users + u0 * 6 + 2);
        float2 b2 = *(const float2*)(users + u0 * 6 + 4);
        w0 = a.x; w1 = a.y; w2 = b2.x; w3 = b2.y;
    }

    for (int stp = 0; stp < NU; ++stp) {
        const int uid = s_order[stp];

        // prefetch next user's mask row + workload
        int   mnx = 0;
        float nw0 = 0.f, nw1 = 0.f, nw2 = 0.f, nw3 = 0.f;
        if (stp + 1 < NU) {
            int u1 = s_order[stp + 1];
            if (byteMode) {
                uchar4 mv = *(const uchar4*)(mbytes + (size_t)u1 * NS + sbase);
                mnx = (mv.x ? 1 : 0) | (mv.y ? 2 : 0) | (mv.z ? 4 : 0) | (mv.w ? 8 : 0);
            } else {
                int4 mv = *(const int4*)(mwords + (size_t)u1 * NS + sbase);
                mnx = (mv.x ? 1 : 0) | (mv.y ? 2 : 0) | (mv.z ? 4 : 0) | (mv.w ? 8 : 0);
            }
            float2 a  = *(const float2*)(users + u1 * 6 + 2);
            float2 b2 = *(const float2*)(users + u1 * 6 + 4);
            nw0 = a.x; nw1 = a.y; nw2 = b2.x; nw3 = b2.y;
        }

        // ---------------- phase A: valid, sum(fuzzy), count, minmax(B), C flags
        int   vbits = 0;
        float sumF = 0.0f, cnt = 0.0f;
        float mxB = -FINF, mnB = FINF;
        int   aC10 = 0, aC0 = 0;
        #pragma unroll
        for (int j = 0; j < 4; ++j) {
            bool valid = ((mcur >> j) & 1) &&
                         (t[j][0] >= w0) && (t[j][1] >= w1) &&
                         (t[j][2] >= w2) && (t[j][3] >= w3);
            if (valid) {
                vbits |= 1 << j;
                sumF += f[j][0] + f[j][1] + f[j][2] + f[j][3];
                cnt  += 1.0f;
                mxB = fmaxf(mxB, B[j]);
                mnB = fminf(mnB, B[j]);
                if (us[j] == 0.0f) aC10 = 1; else aC0 = 1;
            }
        }
        #pragma unroll
        for (int off = 32; off > 0; off >>= 1) {
            sumF += __shfl_xor(sumF, off);
            cnt  += __shfl_xor(cnt, off);
            mxB = fmaxf(mxB, __shfl_xor(mxB, off));
            mnB = fminf(mnB, __shfl_xor(mnB, off));
        }
        unsigned long long b10 = __ballot(aC10);
        unsigned long long b0  = __ballot(aC0);
        if (lane == 0) {
            rA[wid][0] = sumF; rA[wid][1] = cnt;
            rA[wid][2] = mxB;  rA[wid][3] = mnB;
            rA[wid][4] = b10 ? 1.0f : 0.0f;
            rA[wid][5] = b0  ? 1.0f : 0.0f;
        }
        __syncthreads();   // B1
        sumF = rA[0][0] + rA[1][0] + rA[2][0] + rA[3][0];
        cnt  = rA[0][1] + rA[1][1] + rA[2][1] + rA[3][1];
        mxB  = fmaxf(fmaxf(rA[0][2], rA[1][2]), fmaxf(rA[2][2], rA[3][2]));
        mnB  = fminf(fminf(rA[0][3], rA[1][3]), fminf(rA[2][3], rA[3][3]));
        bool hasC10 = (rA[0][4] + rA[1][4] + rA[2][4] + rA[3][4]) > 0.0f;
        bool hasC0  = (rA[0][5] + rA[1][5] + rA[2][5] + rA[3][5]) > 0.0f;

        float alloc = -1.0f;
        if (cnt > 0.0f) {
            // ---------------- phase B: variance (two-pass, matches reference)
            float n = cnt * 4.0f;
            float mean = sumF / fmaxf(n, 1.0f);
            float s2 = 0.0f;
            #pragma unroll
            for (int j = 0; j < 4; ++j) {
                if ((vbits >> j) & 1) {
                    float d0 = f[j][0] - mean;
                    float d1 = f[j][1] - mean;
                    float d2 = f[j][2] - mean;
                    float d3 = f[j][3] - mean;
                    s2 += d0 * d0 + d1 * d1 + d2 * d2 + d3 * d3;
                }
            }
            #pragma unroll
            for (int off = 32; off > 0; off >>= 1) s2 += __shfl_xor(s2, off);
            if (lane == 0) rB[wid] = s2;
            __syncthreads();   // B2
            s2 = rB[0] + rB[1] + rB[2] + rB[3];
            float var = s2 / fmaxf(n - 1.0f, 1.0f);
            float sd  = sqrtf(var);
            int row = (mean <= 0.2f) ? 0 : ((mean <= 0.5f) ? 1 : 2);
            int col = (sd   <= 0.1f) ? 0 : ((sd   <= 0.3f) ? 1 : 2);
            float tw;
            if (row == 0)      tw = (col == 0) ? 0.9f : ((col == 1) ? 0.8f : 0.6f);
            else if (row == 1) tw = (col == 0) ? 0.6f : ((col == 1) ? 0.5f : 0.4f);
            else               tw = (col == 0) ? 0.4f : ((col == 1) ? 0.2f : 0.1f);

            // ---------------- phase C: scores + argmin
            float mxC = hasC10 ? 10.0f : 0.0f;
            float mnC = hasC0  ? 0.0f  : 10.0f;
            float dB = mxB - mnB;
            float dC = mxC - mnC;
            float a  = tw + 0.3f;
            float bb = (1.0f - tw) + 0.55f;
            float ci10 = (dC != 0.0f) ? (10.0f - mnC) / dC : 0.0f;
            float ci0  = (dC != 0.0f) ? (0.0f  - mnC) / dC : 0.0f;
            float bc10 = bb * ci10;
            float bc0  = bb * ci0;

            float bestV = FINF;
            int   bestI = NS;
            #pragma unroll
            for (int j = 0; j < 4; ++j) {
                float bi = (dB != 0.0f) ? (B[j] - mnB) / dB : 0.0f;
                float sc = a * bi + ((us[j] == 0.0f) ? bc10 : bc0);
                bool valid = (vbits >> j) & 1;
                float key = valid ? sc : FINF;
                int idx = sbase + j;
                if (key < bestV || (key == bestV && idx < bestI)) { bestV = key; bestI = idx; }
            }
            #pragma unroll
            for (int off = 32; off > 0; off >>= 1) {
                float ov = __shfl_xor(bestV, off);
                int   oi = __shfl_xor(bestI, off);
                if (ov < bestV || (ov == bestV && oi < bestI)) { bestV = ov; bestI = oi; }
            }
            if (lane == 0) { rCv[wid] = bestV; rCi[wid] = bestI; }
            __syncthreads();   // B3
            bestV = rCv[0]; bestI = rCi[0];
            #pragma unroll
            for (int w = 1; w < 4; ++w) {
                float ov = rCv[w]; int oi = rCi[w];
                if (ov < bestV || (ov == bestV && oi < bestI)) { bestV = ov; bestI = oi; }
            }
            const int chosen = bestI;
            alloc = (float)chosen;

            // ---------------- update chosen server (static register indexing)
            #pragma unroll
            for (int j = 0; j < 4; ++j) {
                if (sbase + j == chosen) {
                    t[j][0] = t[j][0] - w0;
                    t[j][1] = t[j][1] - w1;
                    t[j][2] = t[j][2] - w2;
                    t[j][3] = t[j][3] - w3;
                    us[j] = us[j] + 1.0f;
                    #pragma unroll
                    for (int k = 0; k < 4; ++k) {
                        const float mid  = (k == 0) ? 0.4f : ((k == 1) ? 0.5f : ((k == 2) ? 0.3f : 0.5f));
                        const float high = (k == 0) ? 0.8f : ((k == 1) ? 0.8f : ((k == 2) ? 0.7f : 0.8f));
                        float rem = c[j][k] - t[j][k];
                        float x = rem / c[j][k];
                        float fv;
                        if (x <= 0.0f)      fv = 0.0f;
                        else if (x <= mid)  fv = x / mid;
                        else if (x <= high) fv = (high - x) / (high - mid);
                        else                fv = 0.0f;
                        f[j][k] = fv;
                    }
                    float sB = t[j][0] / c[j][0] + t[j][1] / c[j][1]
                             + t[j][2] / c[j][2] + t[j][3] / c[j][3];
                    B[j] = 1.0f - sB * 0.25f;
                }
            }
        } else {
            __syncthreads();   // close the step: protect rA WAR across steps
        }

        if (tid == 0) {
            out[uid] = alloc;
            if (alloc != -1.0f) allocCnt += 1.0f;
        }
        mcur = mnx; w0 = nw0; w1 = nw1; w2 = nw2; w3 = nw3;
    }

    __syncthreads();
    #pragma unroll
    for (int j = 0; j < 4; ++j) out[NU + sbase + j] = us[j];
    float uc = 0.0f;
    #pragma unroll
    for (int j = 0; j < 4; ++j) uc += (us[j] != 0.0f) ? 1.0f : 0.0f;
    #pragma unroll
    for (int off = 32; off > 0; off >>= 1) uc += __shfl_xor(uc, off);
    if (lane == 0) rB[wid] = uc;
    __syncthreads();
    if (tid == 0) {
        float ut = rB[0] + rB[1] + rB[2] + rB[3];
        out[NU + NS]     = allocCnt / 8192.0f;
        out[NU + NS + 1] = ut / 1024.0f;
    }
}

// ---------------------------------------------------------------------------
extern "C" void kernel_launch(void* const* d_in, const int* in_sizes, int n_in,
                              void* d_out, int out_size, void* d_ws, size_t ws_size,
                              hipStream_t stream) {
    const float* servers = (const float*)d_in[0];
    const float* users   = (const float*)d_in[1];
    const void*  masks   = d_in[2];
    int*   wsi = (int*)d_ws;           // [0] mode flag, [64..64+8191] order
    float* out = (float*)d_out;

    detect_kernel<<<1, 256, 0, stream>>>((const unsigned*)masks, wsi);
    rank_kernel<<<32, 256, 0, stream>>>(users, wsi + 64);
    alloc_kernel<<<1, 256, 0, stream>>>(servers, users, masks, wsi, out);
}